// Round 2
// baseline (105.528 us; speedup 1.0000x reference)
//
#include <hip/hip_runtime.h>
#include <hip/hip_bf16.h>

typedef unsigned short u16;
typedef __attribute__((ext_vector_type(8))) unsigned short ushort8;
typedef __attribute__((ext_vector_type(8))) short short8;
typedef __attribute__((ext_vector_type(4))) float f32x4;

#define DEV __device__ __forceinline__

DEV float b2f(u16 u){ return __uint_as_float(((unsigned)u) << 16); }
DEV u16 f2b(float f){
  unsigned x = __float_as_uint(f);
  return (u16)((x + 0x7fffu + ((x >> 16) & 1u)) >> 16);   // RNE
}
DEV short8 ld8(const u16* p){ return __builtin_bit_cast(short8, *(const ushort8*)p); }
DEV f32x4 mfma(short8 a, short8 b, f32x4 c){
  return __builtin_amdgcn_mfma_f32_16x16x32_bf16(a, b, c, 0, 0, 0);
}
DEV float fast_tanh(float x){
  float e = __expf(2.f * x);
  return 1.f - 2.f / (e + 1.f);
}

// ---- weight pre-transpose + fp32->bf16: wt[n][k] = (bf16)w[k][n], N always 512
__global__ __launch_bounds__(256) void kt6(
    const float* __restrict__ w1, const float* __restrict__ w2,
    const float* __restrict__ w3, const float* __restrict__ w4,
    const float* __restrict__ w5, const float* __restrict__ w6,
    u16* __restrict__ ws)
{
  __shared__ u16 tile[64][72];
  const float* w; u16* wt; int K;
  switch (blockIdx.z) {
    case 0:  w = w1; wt = ws;          K = 256; break;
    case 1:  w = w2; wt = ws + 131072; K = 512; break;
    case 2:  w = w3; wt = ws + 393216; K = 256; break;
    case 3:  w = w4; wt = ws + 524288; K = 512; break;
    case 4:  w = w5; wt = ws + 786432; K = 256; break;
    default: w = w6; wt = ws + 917504; K = 512; break;
  }
  int k0 = blockIdx.y * 64;
  if (k0 >= K) return;                      // uniform per block
  int n0 = blockIdx.x * 64;
  int t = threadIdx.x;
  int r = t >> 2, c0 = (t & 3) * 16;
  const float* src = w + (size_t)(k0 + r) * 512 + n0 + c0;
  #pragma unroll
  for (int jj = 0; jj < 4; ++jj) {
    float4 v = *(const float4*)(src + jj * 4);
    tile[r][c0 + jj*4 + 0] = f2b(v.x);
    tile[r][c0 + jj*4 + 1] = f2b(v.y);
    tile[r][c0 + jj*4 + 2] = f2b(v.z);
    tile[r][c0 + jj*4 + 3] = f2b(v.w);
  }
  __syncthreads();
  ushort8 o0, o1;
  #pragma unroll
  for (int j = 0; j < 8; ++j) { o0[j] = tile[c0 + j][r]; o1[j] = tile[c0 + 8 + j][r]; }
  u16* dst = wt + (size_t)(n0 + r) * K + k0 + c0;
  *(ushort8*)dst       = o0;
  *(ushort8*)(dst + 8) = o1;
}

// ---------------- LDS layout (u16-element offsets), total 79360 els = 155 KB -
#define OFF_V   0        // V  [32][520]
#define OFF_N   16640    // n  [32][264]
#define OFF_T   25088    // t  [32][520]
#define OFF_Q   41728    // Q  [32][520] row-major
#define OFF_K   58368    // K  [32][520] row-major
#define OFF_BT  75008    // beta_time fp32 [32][33] (1056 f32 = 2112 u16)
#define OFF_QT  16640    // Qt [512][40]  (overlays n+t, dead by then)
#define OFF_KT  37120    // Kt [512][40]  (overlays t tail + Qrm, dead)
#define OFF_ET  57600    // E  8 waves x [64][40] (overlays Krm+bt, dead)
#define OFF_AT  78080    // A_time bf16 [32][40]
#define OFF_FT  37120    // featT [512][40] == KT region (wave-local rows)
#define SMEM_ELS 79360

template<int ACT>  // 0 = tanh, 1 = relu
DEV void mlp_branch(const u16* __restrict__ nl, u16* __restrict__ tl, u16* __restrict__ ol,
                    const u16* __restrict__ wA, const float* __restrict__ bA,
                    const u16* __restrict__ wB, const float* __restrict__ bB,
                    int wv, int q, int r16)
{
  const f32x4 Z = {0.f, 0.f, 0.f, 0.f};
  // GEMM1: [32,256] @ [256,512], this wave's 64 cols
  {
    f32x4 acc[2][4];
    #pragma unroll
    for (int mt = 0; mt < 2; ++mt)
      #pragma unroll
      for (int gt = 0; gt < 4; ++gt) acc[mt][gt] = Z;
    const u16* a0p = nl + r16 * 264;
    const u16* a1p = nl + (16 + r16) * 264;
    for (int kk = 0; kk < 8; ++kk) {
      short8 a0 = ld8(a0p + kk*32 + q*8);
      short8 a1 = ld8(a1p + kk*32 + q*8);
      #pragma unroll
      for (int gt = 0; gt < 4; ++gt) {
        int gcol = wv*64 + gt*16 + r16;
        short8 b = ld8(wA + (size_t)gcol*256 + kk*32 + q*8);
        acc[0][gt] = mfma(a0, b, acc[0][gt]);
        acc[1][gt] = mfma(a1, b, acc[1][gt]);
      }
    }
    #pragma unroll
    for (int gt = 0; gt < 4; ++gt) {
      int gcol = wv*64 + gt*16 + r16;
      float bias = bA[gcol];
      #pragma unroll
      for (int mt = 0; mt < 2; ++mt)
        #pragma unroll
        for (int i = 0; i < 4; ++i) {
          float v = acc[mt][gt][i] + bias;
          v = (ACT == 0) ? fast_tanh(v) : fmaxf(v, 0.f);
          tl[(mt*16 + q*4 + i)*520 + gcol] = f2b(v);
        }
    }
  }
  __syncthreads();
  // GEMM2: [32,512] @ [512,512]
  {
    f32x4 acc[2][4];
    #pragma unroll
    for (int mt = 0; mt < 2; ++mt)
      #pragma unroll
      for (int gt = 0; gt < 4; ++gt) acc[mt][gt] = Z;
    const u16* a0p = tl + r16 * 520;
    const u16* a1p = tl + (16 + r16) * 520;
    for (int kk = 0; kk < 16; ++kk) {
      short8 a0 = ld8(a0p + kk*32 + q*8);
      short8 a1 = ld8(a1p + kk*32 + q*8);
      #pragma unroll
      for (int gt = 0; gt < 4; ++gt) {
        int gcol = wv*64 + gt*16 + r16;
        short8 b = ld8(wB + (size_t)gcol*512 + kk*32 + q*8);
        acc[0][gt] = mfma(a0, b, acc[0][gt]);
        acc[1][gt] = mfma(a1, b, acc[1][gt]);
      }
    }
    #pragma unroll
    for (int gt = 0; gt < 4; ++gt) {
      int gcol = wv*64 + gt*16 + r16;
      float bias = bB[gcol];
      #pragma unroll
      for (int mt = 0; mt < 2; ++mt)
        #pragma unroll
        for (int i = 0; i < 4; ++i)
          ol[(mt*16 + q*4 + i)*520 + gcol] = f2b(acc[mt][gt][i] + bias);
    }
  }
}

__global__ __launch_bounds__(512) void fused_main(
    const float* __restrict__ xg, const float* __restrict__ gg, const float* __restrict__ bgm,
    const float* __restrict__ b1, const float* __restrict__ b2, const float* __restrict__ b3,
    const float* __restrict__ b4, const float* __restrict__ b5, const float* __restrict__ b6,
    const u16* __restrict__ wst, float* __restrict__ outg)
{
  __shared__ __align__(16) u16 sm[SMEM_ELS];
  const int tid = threadIdx.x;
  const int bid = blockIdx.x;
  const int wv = tid >> 6, ln = tid & 63, q = ln >> 4, r16 = ln & 15;
  const f32x4 Z = {0.f, 0.f, 0.f, 0.f};
  const float RS512 = 0.04419417382415922f;   // 1/sqrt(512)
  const float RS32  = 0.17677669529663687f;   // 1/sqrt(32)

  // ---- P0: LayerNorm over D=256 (16 threads per row, 16 cols each) ----
  {
    int row = tid >> 4, l16 = tid & 15;
    const float* xr = xg + (size_t)(bid*32 + row)*256 + l16*16;
    float xf[16];
    #pragma unroll
    for (int j = 0; j < 16; j += 4) {
      float4 v = *(const float4*)(xr + j);
      xf[j] = v.x; xf[j+1] = v.y; xf[j+2] = v.z; xf[j+3] = v.w;
    }
    float s = 0.f, ss = 0.f;
    #pragma unroll
    for (int j = 0; j < 16; ++j){ s += xf[j]; ss += xf[j]*xf[j]; }
    #pragma unroll
    for (int m = 1; m < 16; m <<= 1){ s += __shfl_xor(s, m); ss += __shfl_xor(ss, m); }
    float mean = s * (1.f/256.f);
    float var  = ss * (1.f/256.f) - mean*mean;
    float rs   = rsqrtf(var + 1e-5f);
    float gf[16], bf[16];
    #pragma unroll
    for (int j = 0; j < 16; j += 4) {
      float4 gv = *(const float4*)(gg  + l16*16 + j);
      float4 bv = *(const float4*)(bgm + l16*16 + j);
      gf[j] = gv.x; gf[j+1] = gv.y; gf[j+2] = gv.z; gf[j+3] = gv.w;
      bf[j] = bv.x; bf[j+1] = bv.y; bf[j+2] = bv.z; bf[j+3] = bv.w;
    }
    ushort8 o0, o1;
    #pragma unroll
    for (int j = 0; j < 8; ++j){
      o0[j] = f2b((xf[j]   - mean)*rs*gf[j]   + bf[j]);
      o1[j] = f2b((xf[j+8] - mean)*rs*gf[j+8] + bf[j+8]);
    }
    *(ushort8*)(sm + OFF_N + row*264 + l16*16)     = o0;
    *(ushort8*)(sm + OFF_N + row*264 + l16*16 + 8) = o1;
  }
  __syncthreads();

  // ---- P1..P3: Q, K, V ----
  mlp_branch<0>(sm+OFF_N, sm+OFF_T, sm+OFF_Q, wst,          b1, wst + 131072, b2, wv, q, r16);
  __syncthreads();
  mlp_branch<0>(sm+OFF_N, sm+OFF_T, sm+OFF_K, wst + 393216, b3, wst + 524288, b4, wv, q, r16);
  __syncthreads();
  mlp_branch<1>(sm+OFF_N, sm+OFF_T, sm+OFF_V, wst + 786432, b5, wst + 917504, b6, wv, q, r16);
  __syncthreads();

  // ---- P4a: beta_time = Q K^T / sqrt(512), waves 0..3 ----
  float* btf = (float*)(sm + OFF_BT);
  if (wv < 4) {
    int mt = wv >> 1, nt = wv & 1;
    f32x4 acc = Z;
    const u16* qb = sm + OFF_Q + (mt*16 + r16)*520;
    const u16* kb = sm + OFF_K + (nt*16 + r16)*520;
    for (int kk = 0; kk < 16; ++kk)
      acc = mfma(ld8(qb + kk*32 + q*8), ld8(kb + kk*32 + q*8), acc);
    #pragma unroll
    for (int i = 0; i < 4; ++i)
      btf[(mt*16 + q*4 + i)*33 + nt*16 + r16] = acc[i] * RS512;
  }
  __syncthreads();

  // ---- P4b: row softmax -> A_time (bf16) ; P5a: Qt = Q^T ----
  {
    int row = tid >> 4, v2 = tid & 15;
    float v0 = btf[row*33 + v2], v1 = btf[row*33 + v2 + 16];
    float m = fmaxf(v0, v1);
    #pragma unroll
    for (int msk = 1; msk < 16; msk <<= 1) m = fmaxf(m, __shfl_xor(m, msk));
    float e0 = __expf(v0 - m), e1 = __expf(v1 - m);
    float sum = e0 + e1;
    #pragma unroll
    for (int msk = 1; msk < 16; msk <<= 1) sum += __shfl_xor(sum, msk);
    float inv = 1.f / sum;
    sm[OFF_AT + row*40 + v2]      = f2b(e0 * inv);
    sm[OFF_AT + row*40 + v2 + 16] = f2b(e1 * inv);
  }
  {
    int row = tid & 31, cb = (tid >> 5) * 32;
    const u16* src = sm + OFF_Q + row*520 + cb;
    ushort8 v[4];
    #pragma unroll
    for (int jj = 0; jj < 4; ++jj) v[jj] = *(const ushort8*)(src + jj*8);
    #pragma unroll
    for (int jj = 0; jj < 4; ++jj)
      #pragma unroll
      for (int j = 0; j < 8; ++j)
        sm[OFF_QT + (cb + jj*8 + j)*40 + row] = v[jj][j];
  }
  __syncthreads();

  // ---- P5b: Kt = K^T (overlays dead Qrm region) ----
  {
    int row = tid & 31, cb = (tid >> 5) * 32;
    const u16* src = sm + OFF_K + row*520 + cb;
    ushort8 v[4];
    #pragma unroll
    for (int jj = 0; jj < 4; ++jj) v[jj] = *(const ushort8*)(src + jj*8);
    #pragma unroll
    for (int jj = 0; jj < 4; ++jj)
      #pragma unroll
      for (int j = 0; j < 8; ++j)
        sm[OFF_KT + (cb + jj*8 + j)*40 + row] = v[jj][j];
  }
  __syncthreads();

  // ---- P6: feature attention, per wave = 64 columns g ----
  {
    u16* Etw = sm + OFF_ET + wv*2560;     // [64][40] scratch, wave-private
    const int g0 = wv * 64;
    f32x4 facc[2][4];
    #pragma unroll
    for (int mt = 0; mt < 2; ++mt)
      #pragma unroll
      for (int gt = 0; gt < 4; ++gt) facc[mt][gt] = Z;
    float csum[4] = {0.f, 0.f, 0.f, 0.f};
    short8 bK[4];                          // K-dim = w = 32, same frags all tiles
    #pragma unroll
    for (int gt = 0; gt < 4; ++gt)
      bK[gt] = ld8(sm + OFF_KT + (size_t)(g0 + gt*16 + r16)*40 + q*8);

    #pragma unroll 2
    for (int ht = 0; ht < 16; ++ht) {      // h-tiles of 32
      f32x4 sv[2][4];
      #pragma unroll
      for (int smi = 0; smi < 2; ++smi) {
        short8 aQ = ld8(sm + OFF_QT + (ht*32 + smi*16 + r16)*40 + q*8);
        #pragma unroll
        for (int gt = 0; gt < 4; ++gt)
          sv[smi][gt] = mfma(aQ, bK[gt], Z);
      }
      #pragma unroll
      for (int smi = 0; smi < 2; ++smi)
        #pragma unroll
        for (int gt = 0; gt < 4; ++gt)
          #pragma unroll
          for (int i = 0; i < 4; ++i) {
            float e = __expf(sv[smi][gt][i] * RS32);   // no max-sub: |logit| small
            csum[gt] += e;
            Etw[(gt*16 + r16)*40 + smi*16 + q*4 + i] = f2b(e);
          }
      asm volatile("s_waitcnt lgkmcnt(0)" ::: "memory");  // wave-private LDS RAW
      short8 bE[4];
      #pragma unroll
      for (int gt = 0; gt < 4; ++gt)
        bE[gt] = ld8(Etw + (gt*16 + r16)*40 + q*8);
      #pragma unroll
      for (int mt = 0; mt < 2; ++mt) {
        short8 aV = ld8(sm + OFF_V + (mt*16 + r16)*520 + ht*32 + q*8);
        #pragma unroll
        for (int gt = 0; gt < 4; ++gt)
          facc[mt][gt] = mfma(aV, bE[gt], facc[mt][gt]);
      }
    }
    float inv[4];
    #pragma unroll
    for (int gt = 0; gt < 4; ++gt) {
      float cs = csum[gt];
      cs += __shfl_xor(cs, 16);
      cs += __shfl_xor(cs, 32);
      inv[gt] = 1.f / cs;
    }
    // featT over KT region: wave-local rows -> no barrier needed
    #pragma unroll
    for (int mt = 0; mt < 2; ++mt)
      #pragma unroll
      for (int gt = 0; gt < 4; ++gt)
        #pragma unroll
        for (int i = 0; i < 4; ++i) {
          int w = mt*16 + q*4 + i;
          int g = g0 + gt*16 + r16;
          sm[OFF_FT + g*40 + w] = f2b(facc[mt][gt][i] * inv[gt]);
        }
  }

  // ---- P7: out = A_time @ feat ----
  {
    const int g0 = wv * 64;
    short8 aA0 = ld8(sm + OFF_AT + r16*40 + q*8);
    short8 aA1 = ld8(sm + OFF_AT + (16 + r16)*40 + q*8);
    #pragma unroll
    for (int gt = 0; gt < 4; ++gt) {
      short8 bF = ld8(sm + OFF_FT + (size_t)(g0 + gt*16 + r16)*40 + q*8);
      f32x4 o0 = mfma(aA0, bF, Z);
      f32x4 o1 = mfma(aA1, bF, Z);
      #pragma unroll
      for (int i = 0; i < 4; ++i) {
        int g = g0 + gt*16 + r16;
        outg[(size_t)(bid*32 + q*4 + i)*512 + g]      = o0[i];
        outg[(size_t)(bid*32 + 16 + q*4 + i)*512 + g] = o1[i];
      }
    }
  }
}

extern "C" void kernel_launch(void* const* d_in, const int* in_sizes, int n_in,
                              void* d_out, int out_size, void* d_ws, size_t ws_size,
                              hipStream_t stream)
{
  const float* x  = (const float*)d_in[0];
  const float* gm = (const float*)d_in[1];
  const float* bt = (const float*)d_in[2];
  const float* w1 = (const float*)d_in[3];
  const float* b1 = (const float*)d_in[4];
  const float* w2 = (const float*)d_in[5];
  const float* b2 = (const float*)d_in[6];
  const float* w3 = (const float*)d_in[7];
  const float* b3 = (const float*)d_in[8];
  const float* w4 = (const float*)d_in[9];
  const float* b4 = (const float*)d_in[10];
  const float* w5 = (const float*)d_in[11];
  const float* b5 = (const float*)d_in[12];
  const float* w6 = (const float*)d_in[13];
  const float* b6 = (const float*)d_in[14];
  u16* ws  = (u16*)d_ws;
  float* out = (float*)d_out;

  kt6<<<dim3(8, 8, 6), 256, 0, stream>>>(w1, w2, w3, w4, w5, w6, ws);
  fused_main<<<256, 512, 0, stream>>>(x, gm, bt, b1, b2, b3, b4, b5, b6, ws, out);
}